// Round 5
// baseline (13763.036 us; speedup 1.0000x reference)
//
#include <hip/hip_runtime.h>
#include <hip/hip_bf16.h>
#include <stdint.h>

#define BB   64
#define TT   2048
#define II   256
#define HH   256
#define G4   1024   // 4*H
#define NC   10

typedef _Float16 half2v __attribute__((ext_vector_type(2)));
typedef _Float16 half8v __attribute__((ext_vector_type(8)));
typedef float    float4v __attribute__((ext_vector_type(4)));

__device__ __forceinline__ float sigmf(float v) { return 1.f / (1.f + __expf(-v)); }
__device__ __forceinline__ float tanhf2(float v) { float e = __expf(2.f * v); return 1.f - 2.f / (e + 1.f); }

// Barrier WITHOUT vmcnt drain: keeps global xpk loads in flight.
__device__ __forceinline__ void bar_lds() {
  asm volatile("s_waitcnt lgkmcnt(0)\n\ts_barrier" ::: "memory");
}

// ---------------------------------------------------------------------------
// K0a: WcT[g][i] = sum_j key[i][j] * W_ih[g][j]  (f16), biasc[g] = b_ih+b_hh
// ---------------------------------------------------------------------------
__global__ __launch_bounds__(1024) void prep_wc(
    const float* __restrict__ key, const float* __restrict__ Wih,
    const float* __restrict__ bih, const float* __restrict__ bhh,
    _Float16* __restrict__ WcT, float* __restrict__ biasc) {
  __shared__ float krow[II];
  const int i = blockIdx.x;
  const int g = threadIdx.x;
  if (g < II) krow[g] = key[(size_t)i * II + g];
  __syncthreads();
  const float4* w4 = (const float4*)(Wih + (size_t)g * II);
  float acc = 0.f;
#pragma unroll 8
  for (int j = 0; j < II / 4; ++j) {
    float4 w = w4[j];
    acc += w.x * krow[4 * j] + w.y * krow[4 * j + 1] + w.z * krow[4 * j + 2] + w.w * krow[4 * j + 3];
  }
  WcT[(size_t)g * II + i] = (_Float16)acc;
  if (i == 0) biasc[g] = bih[g] + bhh[g];
}

// ---------------------------------------------------------------------------
// K0c: pack W_hh into MFMA A-fragments over GATE-INTERLEAVED rows.
// Interleave: row' = 4k+q  (k = h-elem, q = gate 0..3 -> orig row q*256+k).
// A-frag convention (identical to the verified gemm_xproj):
//   lane holds 8 f16: row = tile_row + (lane&15), k = kt*32 + (lane>>4)*8 + jj.
// Tile (kt 0..7, mg 0..63); wave w = mg>>3 of lstm_seq, m = mg&7.
// RF-resident: kt<5, or kt==5 && m<6  -> wrg[((kt*8+m)*8+w)*64+lane]
// LDS tail (18): (5,6)->0 (5,7)->1 (6,m)->2+m (7,m)->10+m
//                -> wld[(slot*8+w)*64+lane]
// ---------------------------------------------------------------------------
__global__ __launch_bounds__(256) void prep_wfrag(
    const float* __restrict__ Whh, uint4* __restrict__ wrg, uint4* __restrict__ wld) {
  const int id = blockIdx.x * 256 + threadIdx.x;   // 32768 = 8kt * 64mg * 64lane
  const int lane = id & 63;
  const int mg  = (id >> 6) & 63;
  const int kt  = id >> 12;                         // 0..7
  const int w = mg >> 3, m = mg & 7;
  const int rowp = mg * 16 + (lane & 15);           // interleaved row'
  const int g = (rowp & 3) * 256 + (rowp >> 2);     // original gate row
  const int k0 = kt * 32 + (lane >> 4) * 8;
  half8v frag;
#pragma unroll
  for (int jj = 0; jj < 8; ++jj) frag[jj] = (_Float16)Whh[(size_t)g * HH + k0 + jj];
  uint4 u = __builtin_bit_cast(uint4, frag);
  const bool tail = (kt >= 6) || (kt == 5 && m >= 6);
  if (!tail) {
    wrg[((kt * 8 + m) * 8 + w) * 64 + lane] = u;
  } else {
    const int slot = (kt == 5) ? (m - 6) : (2 + (kt - 6) * 8 + m);
    wld[(slot * 8 + w) * 64 + lane] = u;
  }
}

// ---------------------------------------------------------------------------
// K1: packed x-projection GEMM (unchanged from round 4). x_proj[m][g] stored
// at f16 slot (g&255)*4 + (g>>8) = k*4+q : one dwordx2 per h-elem gives
// ((xi,xf),(xg,xo)).
// ---------------------------------------------------------------------------
__global__ __launch_bounds__(256) void gemm_xproj(
    const float* __restrict__ x, const _Float16* __restrict__ WcT,
    const float* __restrict__ biasc, _Float16* __restrict__ xpk) {
  __shared__ __align__(16) _Float16 Asm[128][40];
  __shared__ __align__(16) _Float16 Bsm[128][40];
  const int t = threadIdx.x;
  const int n0 = blockIdx.x * 128;
  const int m0 = blockIdx.y * 128;
  const int r = t >> 1;
  const int hoff = (t & 1) * 16;
  const int lane = t & 63, wave = t >> 6;
  const int quad = lane >> 4, l15 = lane & 15;
  const int mh = (wave & 1) * 64, nh = (wave >> 1) * 64;
  float4v zero = {0.f, 0.f, 0.f, 0.f};
  float4v acc[4][4];
#pragma unroll
  for (int a = 0; a < 4; ++a)
#pragma unroll
    for (int b = 0; b < 4; ++b) acc[a][b] = zero;

  for (int kt = 0; kt < 8; ++kt) {
    const int k0 = kt * 32;
    const float4* xa = (const float4*)(x + (size_t)(m0 + r) * II + k0 + hoff);
    float4 f0 = xa[0], f1 = xa[1], f2 = xa[2], f3 = xa[3];
    half8v lo = {(_Float16)f0.x, (_Float16)f0.y, (_Float16)f0.z, (_Float16)f0.w,
                 (_Float16)f1.x, (_Float16)f1.y, (_Float16)f1.z, (_Float16)f1.w};
    half8v hi = {(_Float16)f2.x, (_Float16)f2.y, (_Float16)f2.z, (_Float16)f2.w,
                 (_Float16)f3.x, (_Float16)f3.y, (_Float16)f3.z, (_Float16)f3.w};
    const half8v* bsrc = (const half8v*)(WcT + (size_t)(n0 + r) * II + k0 + hoff);
    half8v b0 = bsrc[0], b1 = bsrc[1];
    *(half8v*)&Asm[r][hoff]     = lo;
    *(half8v*)&Asm[r][hoff + 8] = hi;
    *(half8v*)&Bsm[r][hoff]     = b0;
    *(half8v*)&Bsm[r][hoff + 8] = b1;
    __syncthreads();
    half8v af[4], bf[4];
#pragma unroll
    for (int mt = 0; mt < 4; ++mt) af[mt] = *(const half8v*)&Asm[mh + mt * 16 + l15][quad * 8];
#pragma unroll
    for (int nt = 0; nt < 4; ++nt) bf[nt] = *(const half8v*)&Bsm[nh + nt * 16 + l15][quad * 8];
#pragma unroll
    for (int mt = 0; mt < 4; ++mt)
#pragma unroll
      for (int nt = 0; nt < 4; ++nt)
        acc[mt][nt] = __builtin_amdgcn_mfma_f32_16x16x32_f16(af[mt], bf[nt], acc[mt][nt], 0, 0, 0);
    __syncthreads();
  }
  _Float16* dst = xpk;
#pragma unroll
  for (int nt = 0; nt < 4; ++nt) {
    const int col = n0 + nh + nt * 16 + l15;
    const float bias = biasc[col];
    const int slot16 = (col & 255) * 4 + (col >> 8);
#pragma unroll
    for (int mt = 0; mt < 4; ++mt) {
      const int mrow = m0 + mh + mt * 16 + quad * 4;
#pragma unroll
      for (int j = 0; j < 4; ++j)
        dst[(size_t)(mrow + j) * 1024 + slot16] = (_Float16)(acc[mt][nt][j] + bias);
    }
  }
}

// ---------------------------------------------------------------------------
// K2: sequential LSTM, 16 BATCHES PER WORKGROUP (4 WGs total).
// The 16 MFMA B-columns carry 16 batches' h vectors -> the per-CU weight
// stream (the structural bottleneck of rounds 0-4: 512 KB W_hh > RF) is
// amortized 16x. Gate-interleaved rows make D thread-local:
//   lane (quad,col), tile m, reg j  =  gate j of h-elem (w*32+m*4+quad),
//   batch bb+col  ->  c/h update entirely in registers, no gate exchange.
// Weights: 46 frags RF (184 dwords; +acc32+c8+x16+misc ~= 252 <= 256 budget
// at 2 waves/SIMD -- sized to FIT this time), 18 frags LDS (144 KB,
// fragment-order => conflict-free ds_read_b128).
// h: LDS in B-frag order (8 KB): write scattered b16 per elem, read one
// b128 per wave per kt. Two barriers/step, no vmcnt drain.
// ---------------------------------------------------------------------------
__global__ __launch_bounds__(512, 2) void lstm_seq(
    const uint2* __restrict__ xpk, const uint4* __restrict__ wrg,
    const uint4* __restrict__ wld, float* __restrict__ hfin) {
  __shared__ __align__(16) uint4 wsm[18 * 512];        // 147456 B weight tail
  __shared__ __align__(16) _Float16 hfr[4096];         // 8 KB h, B-frag order
  const int t0 = threadIdx.x;
  const int w = t0 >> 6, lane = t0 & 63;
  const int l15 = lane & 15, quad = lane >> 4;
  const int bb = blockIdx.x * 16;

  half8v wA[46];                                       // kt*8+m, holes are tail
#pragma unroll
  for (int kt = 0; kt < 6; ++kt)
#pragma unroll
    for (int m = 0; m < 8; ++m) {
      if (kt == 5 && m >= 6) continue;
      wA[kt * 8 + m] = __builtin_bit_cast(half8v, wrg[((kt * 8 + m) * 8 + w) * 64 + lane]);
    }
#pragma unroll
  for (int i = 0; i < 18; ++i) wsm[i * 512 + t0] = wld[i * 512 + t0];
#pragma unroll
  for (int i = 0; i < 4; ++i) ((uint32_t*)hfr)[i * 512 + t0] = 0;  // h(-1)=0

  float c0 = 0.f, c1 = 0.f, c2 = 0.f, c3 = 0.f, c4 = 0.f, c5 = 0.f, c6 = 0.f, c7 = 0.f;
  const size_t xbase = ((size_t)(bb + l15) * TT) * 256 + (size_t)(w * 32 + quad);
  __syncthreads();

  const float4v zero = {0.f, 0.f, 0.f, 0.f};
  for (int t = 0; t < TT; ++t) {
    const size_t xo = xbase + (size_t)t * 256;
    uint2 x0 = xpk[xo], x1 = xpk[xo + 4], x2 = xpk[xo + 8], x3 = xpk[xo + 12];
    uint2 x4, x5, x6, x7;
    float4v acc[8];
#pragma unroll
    for (int kt = 0; kt < 8; ++kt) {
      half8v hb = *(const half8v*)&hfr[kt * 512 + lane * 8];   // B-frag (conflict-free)
      if (kt == 6) { x4 = xpk[xo + 16]; x5 = xpk[xo + 20]; x6 = xpk[xo + 24]; x7 = xpk[xo + 28]; }
#pragma unroll
      for (int m = 0; m < 8; ++m) {
        half8v wf;
        if (kt < 5 || (kt == 5 && m < 6)) {
          wf = wA[kt * 8 + m];
        } else {
          const int slot = (kt == 5) ? (m - 6) : (2 + (kt - 6) * 8 + m);
          wf = __builtin_bit_cast(half8v, wsm[slot * 512 + t0]);
        }
        acc[m] = __builtin_amdgcn_mfma_f32_16x16x32_f16(wf, hb, (kt == 0) ? zero : acc[m], 0, 0, 0);
      }
    }
    bar_lds();                                    // all B-frag reads done
#define EPI(m, xv, cs)                                                        \
    {                                                                         \
      half2v xa = __builtin_bit_cast(half2v, (xv).x);  /* (xi, xf) */         \
      half2v xb = __builtin_bit_cast(half2v, (xv).y);  /* (xg, xo) */         \
      float ig = sigmf(acc[m][0] + (float)xa.x);                              \
      float fg = sigmf(acc[m][1] + (float)xa.y);                              \
      float gg = tanhf2(acc[m][2] + (float)xb.x);                             \
      float og = sigmf(acc[m][3] + (float)xb.y);                              \
      cs = fg * cs + ig * gg;                                                 \
      float hh = og * tanhf2(cs);                                             \
      const int ke = (m) * 4 + quad;                                          \
      hfr[w * 512 + ((ke >> 3) * 16 + l15) * 8 + (ke & 7)] = (_Float16)hh;    \
      if (t == TT - 1) hfin[(size_t)(bb + l15) * HH + (w * 32 + ke)] = hh;    \
    }
    EPI(0, x0, c0) EPI(1, x1, c1) EPI(2, x2, c2) EPI(3, x3, c3)
    EPI(4, x4, c4) EPI(5, x5, c5) EPI(6, x6, c6) EPI(7, x7, c7)
#undef EPI
    bar_lds();                                    // h(t) visible to all
  }
}

// ---------------------------------------------------------------------------
// K3: out[b][c] = h_last[b] . W_cls[c] + b_cls[c]
// ---------------------------------------------------------------------------
__global__ __launch_bounds__(256) void cls_k(
    const float* __restrict__ hfin, const float* __restrict__ Wcls,
    const float* __restrict__ bcls, float* __restrict__ out) {
  __shared__ float part[4][NC];
  const int b = blockIdx.x, tid = threadIdx.x;
  const int lane = tid & 63, wave = tid >> 6;
  float hv = hfin[(size_t)b * HH + tid];
#pragma unroll
  for (int c = 0; c < NC; ++c) {
    float p = hv * Wcls[c * HH + tid];
#pragma unroll
    for (int off = 32; off >= 1; off >>= 1) p += __shfl_down(p, off, 64);
    if (lane == 0) part[wave][c] = p;
  }
  __syncthreads();
  if (tid < NC) {
    out[(size_t)b * NC + tid] =
        part[0][tid] + part[1][tid] + part[2][tid] + part[3][tid] + bcls[tid];
  }
}

// ---------------------------------------------------------------------------
extern "C" void kernel_launch(void* const* d_in, const int* in_sizes, int n_in,
                              void* d_out, int out_size, void* d_ws, size_t ws_size,
                              hipStream_t stream) {
  (void)in_sizes; (void)n_in; (void)out_size; (void)ws_size;
  const float* x    = (const float*)d_in[0];
  const float* key  = (const float*)d_in[1];
  const float* Wih  = (const float*)d_in[2];
  const float* Whh  = (const float*)d_in[3];
  const float* bih  = (const float*)d_in[4];
  const float* bhh  = (const float*)d_in[5];
  const float* Wcls = (const float*)d_in[6];
  const float* bcls = (const float*)d_in[7];
  float* out = (float*)d_out;

  char* ws = (char*)d_ws;
  size_t off = 0;
  uint2* xpk     = (uint2*)(ws + off);    off += (size_t)BB * TT * 512 * 4;   // 268 MB
  uint4* wrg     = (uint4*)(ws + off);    off += (size_t)48 * 8 * 64 * 16;    // 393 KB (holes ok)
  uint4* wld     = (uint4*)(ws + off);    off += (size_t)18 * 8 * 64 * 16;    // 147 KB
  _Float16* WcT  = (_Float16*)(ws + off); off += (size_t)G4 * II * 2;
  float* biasc   = (float*)(ws + off);    off += (size_t)G4 * 4;
  float* hfin    = (float*)(ws + off);    off += (size_t)BB * HH * 4;

  hipLaunchKernelGGL(prep_wc,    dim3(II),  dim3(G4),  0, stream, key, Wih, bih, bhh, WcT, biasc);
  hipLaunchKernelGGL(prep_wfrag, dim3(128), dim3(256), 0, stream, Whh, wrg, wld);
  hipLaunchKernelGGL(gemm_xproj, dim3(G4 / 128, (BB * TT) / 128), dim3(256), 0, stream,
                     x, WcT, biasc, (_Float16*)xpk);
  hipLaunchKernelGGL(lstm_seq, dim3(BB / 16), dim3(512), 0, stream,
                     xpk, wrg, wld, hfin);
  hipLaunchKernelGGL(cls_k,    dim3(BB), dim3(256), 0, stream, hfin, Wcls, bcls, out);
}

// Round 6
// 12993.983 us; speedup vs baseline: 1.0592x; 1.0592x over previous
//
#include <hip/hip_runtime.h>
#include <hip/hip_bf16.h>
#include <stdint.h>

#define BB   64
#define TT   2048
#define II   256
#define HH   256
#define G4   1024   // 4*H
#define NC   10

typedef _Float16 half2v __attribute__((ext_vector_type(2)));
typedef _Float16 half8v __attribute__((ext_vector_type(8)));
typedef float    float4v __attribute__((ext_vector_type(4)));

__device__ __forceinline__ float sigmf(float v) { return 1.f / (1.f + __expf(-v)); }
__device__ __forceinline__ float tanhf2(float v) { float e = __expf(2.f * v); return 1.f - 2.f / (e + 1.f); }

// Barrier WITHOUT vmcnt drain: keeps global xpk loads in flight.
__device__ __forceinline__ void bar_lds() {
  asm volatile("s_waitcnt lgkmcnt(0)\n\ts_barrier" ::: "memory");
}

// ---------------------------------------------------------------------------
// K0a: WcT[g][i] = sum_j key[i][j] * W_ih[g][j]  (f16), biasc[g] = b_ih+b_hh
// ---------------------------------------------------------------------------
__global__ __launch_bounds__(1024) void prep_wc(
    const float* __restrict__ key, const float* __restrict__ Wih,
    const float* __restrict__ bih, const float* __restrict__ bhh,
    _Float16* __restrict__ WcT, float* __restrict__ biasc) {
  __shared__ float krow[II];
  const int i = blockIdx.x;
  const int g = threadIdx.x;
  if (g < II) krow[g] = key[(size_t)i * II + g];
  __syncthreads();
  const float4* w4 = (const float4*)(Wih + (size_t)g * II);
  float acc = 0.f;
#pragma unroll 8
  for (int j = 0; j < II / 4; ++j) {
    float4 w = w4[j];
    acc += w.x * krow[4 * j] + w.y * krow[4 * j + 1] + w.z * krow[4 * j + 2] + w.w * krow[4 * j + 3];
  }
  WcT[(size_t)g * II + i] = (_Float16)acc;
  if (i == 0) biasc[g] = bih[g] + bhh[g];
}

// ---------------------------------------------------------------------------
// K0c: pack W_hh into MFMA A-fragments over GATE-INTERLEAVED rows.
// (verified passing in round 5 -- unchanged)
// Interleave: row' = 4k+q  (k = h-elem, q = gate 0..3 -> orig row q*256+k).
// RF-resident: kt<5, or kt==5 && m<6  -> wrg[((kt*8+m)*8+w)*64+lane]
// LDS tail (18): (5,6)->0 (5,7)->1 (6,m)->2+m (7,m)->10+m
// ---------------------------------------------------------------------------
__global__ __launch_bounds__(256) void prep_wfrag(
    const float* __restrict__ Whh, uint4* __restrict__ wrg, uint4* __restrict__ wld) {
  const int id = blockIdx.x * 256 + threadIdx.x;   // 32768 = 8kt * 64mg * 64lane
  const int lane = id & 63;
  const int mg  = (id >> 6) & 63;
  const int kt  = id >> 12;                         // 0..7
  const int w = mg >> 3, m = mg & 7;
  const int rowp = mg * 16 + (lane & 15);           // interleaved row'
  const int g = (rowp & 3) * 256 + (rowp >> 2);     // original gate row
  const int k0 = kt * 32 + (lane >> 4) * 8;
  half8v frag;
#pragma unroll
  for (int jj = 0; jj < 8; ++jj) frag[jj] = (_Float16)Whh[(size_t)g * HH + k0 + jj];
  uint4 u = __builtin_bit_cast(uint4, frag);
  const bool tail = (kt >= 6) || (kt == 5 && m >= 6);
  if (!tail) {
    wrg[((kt * 8 + m) * 8 + w) * 64 + lane] = u;
  } else {
    const int slot = (kt == 5) ? (m - 6) : (2 + (kt - 6) * 8 + m);
    wld[(slot * 8 + w) * 64 + lane] = u;
  }
}

// ---------------------------------------------------------------------------
// K1: packed x-projection GEMM. NEW xpk layout, co-designed with lstm_seq's
// wave shape so its loads are fully coalesced:
//   uint2 index = (grp*TT + t)*4096 + ((w*8+m)*4+quad)*16 + l15
//   where grp=b>>4, l15=b&15, and (w,m,quad) address h-elem ke=w*32+m*4+quad.
//   uint2 = ((xi,xf),(xg,xo)) f16 pairs for that (b,t,ke).
// A lstm wave (lane = quad*16+l15) reading fixed (w,m) touches 64 consecutive
// uint2 = 512 B -> 1 coalesced transaction (round 5's layout split into >=16).
// ---------------------------------------------------------------------------
__global__ __launch_bounds__(256) void gemm_xproj(
    const float* __restrict__ x, const _Float16* __restrict__ WcT,
    const float* __restrict__ biasc, _Float16* __restrict__ xpk) {
  __shared__ __align__(16) _Float16 Asm[128][40];
  __shared__ __align__(16) _Float16 Bsm[128][40];
  const int t = threadIdx.x;
  const int n0 = blockIdx.x * 128;
  const int m0 = blockIdx.y * 128;
  const int r = t >> 1;
  const int hoff = (t & 1) * 16;
  const int lane = t & 63, wave = t >> 6;
  const int quad = lane >> 4, l15 = lane & 15;
  const int mh = (wave & 1) * 64, nh = (wave >> 1) * 64;
  float4v zero = {0.f, 0.f, 0.f, 0.f};
  float4v acc[4][4];
#pragma unroll
  for (int a = 0; a < 4; ++a)
#pragma unroll
    for (int b = 0; b < 4; ++b) acc[a][b] = zero;

  for (int kt = 0; kt < 8; ++kt) {
    const int k0 = kt * 32;
    const float4* xa = (const float4*)(x + (size_t)(m0 + r) * II + k0 + hoff);
    float4 f0 = xa[0], f1 = xa[1], f2 = xa[2], f3 = xa[3];
    half8v lo = {(_Float16)f0.x, (_Float16)f0.y, (_Float16)f0.z, (_Float16)f0.w,
                 (_Float16)f1.x, (_Float16)f1.y, (_Float16)f1.z, (_Float16)f1.w};
    half8v hi = {(_Float16)f2.x, (_Float16)f2.y, (_Float16)f2.z, (_Float16)f2.w,
                 (_Float16)f3.x, (_Float16)f3.y, (_Float16)f3.z, (_Float16)f3.w};
    const half8v* bsrc = (const half8v*)(WcT + (size_t)(n0 + r) * II + k0 + hoff);
    half8v b0 = bsrc[0], b1 = bsrc[1];
    *(half8v*)&Asm[r][hoff]     = lo;
    *(half8v*)&Asm[r][hoff + 8] = hi;
    *(half8v*)&Bsm[r][hoff]     = b0;
    *(half8v*)&Bsm[r][hoff + 8] = b1;
    __syncthreads();
    half8v af[4], bf[4];
#pragma unroll
    for (int mt = 0; mt < 4; ++mt) af[mt] = *(const half8v*)&Asm[mh + mt * 16 + l15][quad * 8];
#pragma unroll
    for (int nt = 0; nt < 4; ++nt) bf[nt] = *(const half8v*)&Bsm[nh + nt * 16 + l15][quad * 8];
#pragma unroll
    for (int mt = 0; mt < 4; ++mt)
#pragma unroll
      for (int nt = 0; nt < 4; ++nt)
        acc[mt][nt] = __builtin_amdgcn_mfma_f32_16x16x32_f16(af[mt], bf[nt], acc[mt][nt], 0, 0, 0);
    __syncthreads();
  }
  _Float16* dst = xpk;
#pragma unroll
  for (int nt = 0; nt < 4; ++nt) {
    const int col = n0 + nh + nt * 16 + l15;
    const float bias = biasc[col];
    const int ke = col & 255, q = col >> 8;
    const int slot = (((ke >> 5) * 8 + ((ke >> 2) & 7)) * 4) + (ke & 3);  // (w*8+m)*4+quad
#pragma unroll
    for (int mt = 0; mt < 4; ++mt) {
      const int mrow = m0 + mh + mt * 16 + quad * 4;
#pragma unroll
      for (int j = 0; j < 4; ++j) {
        const int rr = mrow + j;
        const int b = rr >> 11, tt = rr & 2047;
        dst[(((size_t)(b >> 4) * TT + tt) * 4096 + (size_t)slot * 16 + (b & 15)) * 4 + q] =
            (_Float16)(acc[mt][nt][j] + bias);
      }
    }
  }
}

// ---------------------------------------------------------------------------
// K2: sequential LSTM, 16 batches/WG (4 WGs). Structure verified in round 5;
// this round fixes its two data-motion sins:
//  (1) xpk loads now fully coalesced (layout above): 8 x 512B wave-loads/step
//      instead of 64 instrs x 16 split transactions (round 5's dominant cost).
//  (2) h-writes packed: lanes quad0..3 hold consecutive h elems k=4m..4m+3;
//      two shfl_xor (16,32) gather them into quad0 which does ONE aligned
//      ds_write_b64 into B-frag order (2-way bank alias = free) -- replaces
//      8 scattered b16 writes (round 5's 1.05M bank-conflict cycles).
// Weights: 46 frags RF/AGPR (MFMA reads AGPR A-operands directly),
// 18 frags LDS tail (144 KB, conflict-free b128). Two barriers/step,
// no vmcnt drain.
// ---------------------------------------------------------------------------
__global__ __launch_bounds__(512, 2) void lstm_seq(
    const uint2* __restrict__ xpk, const uint4* __restrict__ wrg,
    const uint4* __restrict__ wld, float* __restrict__ hfin) {
  __shared__ __align__(16) uint4 wsm[18 * 512];        // 147456 B weight tail
  __shared__ __align__(16) _Float16 hfr[4096];         // 8 KB h, B-frag order
  const int t0 = threadIdx.x;
  const int w = t0 >> 6, lane = t0 & 63;
  const int l15 = lane & 15, quad = lane >> 4;
  const int bb = blockIdx.x * 16;

  half8v wA[46];                                       // kt*8+m, holes are tail
#pragma unroll
  for (int kt = 0; kt < 6; ++kt)
#pragma unroll
    for (int m = 0; m < 8; ++m) {
      if (kt == 5 && m >= 6) continue;
      wA[kt * 8 + m] = __builtin_bit_cast(half8v, wrg[((kt * 8 + m) * 8 + w) * 64 + lane]);
    }
#pragma unroll
  for (int i = 0; i < 18; ++i) wsm[i * 512 + t0] = wld[i * 512 + t0];
#pragma unroll
  for (int i = 0; i < 4; ++i) ((uint32_t*)hfr)[i * 512 + t0] = 0;  // h(-1)=0

  float c0 = 0.f, c1 = 0.f, c2 = 0.f, c3 = 0.f, c4 = 0.f, c5 = 0.f, c6 = 0.f, c7 = 0.f;
  // coalesced x base: per (t,m) the wave reads 64 consecutive uint2.
  const uint2* xg = xpk + (size_t)blockIdx.x * TT * 4096 + w * 512 + lane;
  __syncthreads();

  const float4v zero = {0.f, 0.f, 0.f, 0.f};
  for (int t = 0; t < TT; ++t) {
    const uint2* xt = xg + (size_t)t * 4096;
    uint2 x0 = xt[0],   x1 = xt[64],  x2 = xt[128], x3 = xt[192];
    uint2 x4 = xt[256], x5 = xt[320], x6 = xt[384], x7 = xt[448];
    float4v acc[8];
#pragma unroll
    for (int kt = 0; kt < 8; ++kt) {
      half8v hb = *(const half8v*)&hfr[kt * 512 + lane * 8];   // B-frag (conflict-free)
#pragma unroll
      for (int m = 0; m < 8; ++m) {
        half8v wf;
        if (kt < 5 || (kt == 5 && m < 6)) {
          wf = wA[kt * 8 + m];
        } else {
          const int slot = (kt == 5) ? (m - 6) : (2 + (kt - 6) * 8 + m);
          wf = __builtin_bit_cast(half8v, wsm[slot * 512 + t0]);
        }
        acc[m] = __builtin_amdgcn_mfma_f32_16x16x32_f16(wf, hb, (kt == 0) ? zero : acc[m], 0, 0, 0);
      }
    }
    bar_lds();                                    // all B-frag reads done
#define EPI(m, xv, cs)                                                        \
    {                                                                         \
      half2v xa = __builtin_bit_cast(half2v, (xv).x);  /* (xi, xf) */         \
      half2v xb = __builtin_bit_cast(half2v, (xv).y);  /* (xg, xo) */         \
      float ig = sigmf(acc[m][0] + (float)xa.x);                              \
      float fg = sigmf(acc[m][1] + (float)xa.y);                              \
      float gg = tanhf2(acc[m][2] + (float)xb.x);                             \
      float og = sigmf(acc[m][3] + (float)xb.y);                              \
      cs = fg * cs + ig * gg;                                                 \
      float hh = og * tanhf2(cs);                                             \
      _Float16 hf = (_Float16)hh;                                             \
      uint32_t u = (uint32_t)__builtin_bit_cast(unsigned short, hf);          \
      uint32_t pA = u | (((uint32_t)__shfl_xor((int)u, 16, 64)) << 16);       \
      uint32_t pB = (uint32_t)__shfl_xor((int)pA, 32, 64);                    \
      if (quad == 0) {                                                        \
        uint2 pv; pv.x = pA; pv.y = pB;                                       \
        *(uint2*)&hfr[w * 512 + (((m) >> 1) * 16 + l15) * 8 + ((m) & 1) * 4] = pv; \
      }                                                                       \
      if (t == TT - 1) hfin[(size_t)(bb + l15) * HH + (w * 32 + (m) * 4 + quad)] = hh; \
    }
    EPI(0, x0, c0) EPI(1, x1, c1) EPI(2, x2, c2) EPI(3, x3, c3)
    EPI(4, x4, c4) EPI(5, x5, c5) EPI(6, x6, c6) EPI(7, x7, c7)
#undef EPI
    bar_lds();                                    // h(t) visible to all
  }
}

// ---------------------------------------------------------------------------
// K3: out[b][c] = h_last[b] . W_cls[c] + b_cls[c]
// ---------------------------------------------------------------------------
__global__ __launch_bounds__(256) void cls_k(
    const float* __restrict__ hfin, const float* __restrict__ Wcls,
    const float* __restrict__ bcls, float* __restrict__ out) {
  __shared__ float part[4][NC];
  const int b = blockIdx.x, tid = threadIdx.x;
  const int lane = tid & 63, wave = tid >> 6;
  float hv = hfin[(size_t)b * HH + tid];
#pragma unroll
  for (int c = 0; c < NC; ++c) {
    float p = hv * Wcls[c * HH + tid];
#pragma unroll
    for (int off = 32; off >= 1; off >>= 1) p += __shfl_down(p, off, 64);
    if (lane == 0) part[wave][c] = p;
  }
  __syncthreads();
  if (tid < NC) {
    out[(size_t)b * NC + tid] =
        part[0][tid] + part[1][tid] + part[2][tid] + part[3][tid] + bcls[tid];
  }
}

// ---------------------------------------------------------------------------
extern "C" void kernel_launch(void* const* d_in, const int* in_sizes, int n_in,
                              void* d_out, int out_size, void* d_ws, size_t ws_size,
                              hipStream_t stream) {
  (void)in_sizes; (void)n_in; (void)out_size; (void)ws_size;
  const float* x    = (const float*)d_in[0];
  const float* key  = (const float*)d_in[1];
  const float* Wih  = (const float*)d_in[2];
  const float* Whh  = (const float*)d_in[3];
  const float* bih  = (const float*)d_in[4];
  const float* bhh  = (const float*)d_in[5];
  const float* Wcls = (const float*)d_in[6];
  const float* bcls = (const float*)d_in[7];
  float* out = (float*)d_out;

  char* ws = (char*)d_ws;
  size_t off = 0;
  uint2* xpk     = (uint2*)(ws + off);    off += (size_t)BB * TT * 512 * 4;   // 268 MB
  uint4* wrg     = (uint4*)(ws + off);    off += (size_t)48 * 8 * 64 * 16;    // 393 KB (holes ok)
  uint4* wld     = (uint4*)(ws + off);    off += (size_t)18 * 8 * 64 * 16;    // 147 KB
  _Float16* WcT  = (_Float16*)(ws + off); off += (size_t)G4 * II * 2;
  float* biasc   = (float*)(ws + off);    off += (size_t)G4 * 4;
  float* hfin    = (float*)(ws + off);    off += (size_t)BB * HH * 4;

  hipLaunchKernelGGL(prep_wc,    dim3(II),  dim3(G4),  0, stream, key, Wih, bih, bhh, WcT, biasc);
  hipLaunchKernelGGL(prep_wfrag, dim3(128), dim3(256), 0, stream, Whh, wrg, wld);
  hipLaunchKernelGGL(gemm_xproj, dim3(G4 / 128, (BB * TT) / 128), dim3(256), 0, stream,
                     x, WcT, biasc, (_Float16*)xpk);
  hipLaunchKernelGGL(lstm_seq, dim3(BB / 16), dim3(512), 0, stream,
                     xpk, wrg, wld, hfin);
  hipLaunchKernelGGL(cls_k,    dim3(BB), dim3(256), 0, stream, hfin, Wcls, bcls, out);
}

// Round 7
// 4197.927 us; speedup vs baseline: 3.2785x; 3.0953x over previous
//
#include <hip/hip_runtime.h>
#include <hip/hip_bf16.h>
#include <stdint.h>

#define BB   64
#define TT   2048
#define II   256
#define HH   256
#define G4   1024   // 4*H
#define NC   10

typedef _Float16 half2v __attribute__((ext_vector_type(2)));
typedef _Float16 half8v __attribute__((ext_vector_type(8)));
typedef float    float4v __attribute__((ext_vector_type(4)));

__device__ __forceinline__ float fdot2(uint32_t w, uint32_t h, float acc) {
  return __builtin_amdgcn_fdot2(__builtin_bit_cast(half2v, w),
                                __builtin_bit_cast(half2v, h), acc, false);
}
__device__ __forceinline__ float sigmf(float v) { return 1.f / (1.f + __expf(-v)); }
__device__ __forceinline__ float tanhf2(float v) { float e = __expf(2.f * v); return 1.f - 2.f / (e + 1.f); }

// Barrier WITHOUT vmcnt drain: keeps the global xpk prefetch in flight.
__device__ __forceinline__ void bar_lds() {
  asm volatile("s_waitcnt lgkmcnt(0)\n\ts_barrier" ::: "memory");
}

// ---------------------------------------------------------------------------
// K0a: WcT[g][i] = sum_j key[i][j] * W_ih[g][j]  (f16), biasc[g] = b_ih+b_hh
// ---------------------------------------------------------------------------
__global__ __launch_bounds__(1024) void prep_wc(
    const float* __restrict__ key, const float* __restrict__ Wih,
    const float* __restrict__ bih, const float* __restrict__ bhh,
    _Float16* __restrict__ WcT, float* __restrict__ biasc) {
  __shared__ float krow[II];
  const int i = blockIdx.x;
  const int g = threadIdx.x;
  if (g < II) krow[g] = key[(size_t)i * II + g];
  __syncthreads();
  const float4* w4 = (const float4*)(Wih + (size_t)g * II);
  float acc = 0.f;
#pragma unroll 8
  for (int j = 0; j < II / 4; ++j) {
    float4 w = w4[j];
    acc += w.x * krow[4 * j] + w.y * krow[4 * j + 1] + w.z * krow[4 * j + 2] + w.w * krow[4 * j + 3];
  }
  WcT[(size_t)g * II + i] = (_Float16)acc;
  if (i == 0) biasc[g] = bih[g] + bhh[g];
}

// ---------------------------------------------------------------------------
// K0c: pack W_hh f16-pair dwords.
//   kp 0..111  -> wrg[kp][g]                (register-resident in lstm_seq)
//   kp 112..127-> wld[(c*512+t)*4+j] 16B blk (LDS-resident in lstm_seq)
//     where t = g&511, c = (g>>9)*4 + (kp-112)/4, j = (kp-112)&3
// ---------------------------------------------------------------------------
__global__ __launch_bounds__(256) void prep_whh(
    const float* __restrict__ Whh, uint32_t* __restrict__ wrg, uint32_t* __restrict__ wld) {
  const int id = blockIdx.x * 256 + threadIdx.x;   // 131072 = 1024 rows * 128 kp
  const int g  = id & (G4 - 1);
  const int kp = id >> 10;                          // 0..127
  float a = Whh[(size_t)g * HH + 2 * kp];
  float b = Whh[(size_t)g * HH + 2 * kp + 1];
  half2v h = {(_Float16)a, (_Float16)b};
  uint32_t packed = __builtin_bit_cast(uint32_t, h);
  if (kp < 112) {
    wrg[kp * G4 + g] = packed;
  } else {
    const int t = g & 511, hh = g >> 9;
    const int d = kp - 112;                         // 0..15
    const int c = hh * 4 + (d >> 2), j = d & 3;
    wld[(size_t)(c * 512 + t) * 4 + j] = packed;
  }
}

// ---------------------------------------------------------------------------
// K1: packed x-projection GEMM. Logical x_proj[m][g]; stored as [m][512]
// dwords: dword d = (x_proj[m][d], x_proj[m][d+512]) as f16 pair.
// ---------------------------------------------------------------------------
__global__ __launch_bounds__(256) void gemm_xproj(
    const float* __restrict__ x, const _Float16* __restrict__ WcT,
    const float* __restrict__ biasc, _Float16* __restrict__ xpk) {
  __shared__ __align__(16) _Float16 Asm[128][40];
  __shared__ __align__(16) _Float16 Bsm[128][40];
  const int t = threadIdx.x;
  const int n0 = blockIdx.x * 128;
  const int m0 = blockIdx.y * 128;
  const int r = t >> 1;
  const int hoff = (t & 1) * 16;
  const int lane = t & 63, wave = t >> 6;
  const int quad = lane >> 4, l15 = lane & 15;
  const int mh = (wave & 1) * 64, nh = (wave >> 1) * 64;
  float4v zero = {0.f, 0.f, 0.f, 0.f};
  float4v acc[4][4];
#pragma unroll
  for (int a = 0; a < 4; ++a)
#pragma unroll
    for (int b = 0; b < 4; ++b) acc[a][b] = zero;

  for (int kt = 0; kt < 8; ++kt) {
    const int k0 = kt * 32;
    const float4* xa = (const float4*)(x + (size_t)(m0 + r) * II + k0 + hoff);
    float4 f0 = xa[0], f1 = xa[1], f2 = xa[2], f3 = xa[3];
    half8v lo = {(_Float16)f0.x, (_Float16)f0.y, (_Float16)f0.z, (_Float16)f0.w,
                 (_Float16)f1.x, (_Float16)f1.y, (_Float16)f1.z, (_Float16)f1.w};
    half8v hi = {(_Float16)f2.x, (_Float16)f2.y, (_Float16)f2.z, (_Float16)f2.w,
                 (_Float16)f3.x, (_Float16)f3.y, (_Float16)f3.z, (_Float16)f3.w};
    const half8v* bsrc = (const half8v*)(WcT + (size_t)(n0 + r) * II + k0 + hoff);
    half8v b0 = bsrc[0], b1 = bsrc[1];
    *(half8v*)&Asm[r][hoff]     = lo;
    *(half8v*)&Asm[r][hoff + 8] = hi;
    *(half8v*)&Bsm[r][hoff]     = b0;
    *(half8v*)&Bsm[r][hoff + 8] = b1;
    __syncthreads();
    half8v af[4], bf[4];
#pragma unroll
    for (int mt = 0; mt < 4; ++mt) af[mt] = *(const half8v*)&Asm[mh + mt * 16 + l15][quad * 8];
#pragma unroll
    for (int nt = 0; nt < 4; ++nt) bf[nt] = *(const half8v*)&Bsm[nh + nt * 16 + l15][quad * 8];
#pragma unroll
    for (int mt = 0; mt < 4; ++mt)
#pragma unroll
      for (int nt = 0; nt < 4; ++nt)
        acc[mt][nt] = __builtin_amdgcn_mfma_f32_16x16x32_f16(af[mt], bf[nt], acc[mt][nt], 0, 0, 0);
    __syncthreads();
  }
  _Float16* dst = xpk;
#pragma unroll
  for (int nt = 0; nt < 4; ++nt) {
    const int col = n0 + nh + nt * 16 + l15;
    const float bias = biasc[col];
    const int cslot = (col & 511) * 2 + (col >> 9);
#pragma unroll
    for (int mt = 0; mt < 4; ++mt) {
      const int mrow = m0 + mh + mt * 16 + quad * 4;
#pragma unroll
      for (int j = 0; j < 4; ++j)
        dst[(size_t)(mrow + j) * 1024 + cslot] = (_Float16)(acc[mt][nt][j] + bias);
    }
  }
}

// ---------------------------------------------------------------------------
// K2: sequential LSTM (the verified 3785 us configuration, round 1).
// One WG / batch element; 512 threads (8 waves, 2/SIMD); thread t0 owns rows
// t0 and t0+512. Weights: 112 kpairs/row x 2 rows = 224 dwords/thread
// (128 arch VGPR + ~remainder AGPR-parked by the allocator -- the measured
// optimum across KREG={96,104-equivalent,112} probes), tail 16 kpairs/row in
// LDS (64 KB). h broadcast: 1 ds_read_b64/lane + 128 v_readlane -> SGPR,
// fdot2 consumes the SGPR operand. Producers pre-activate f/o before the
// barrier; one float2 LDS exchange; two barriers/step, no vmcnt drain.
// ---------------------------------------------------------------------------
__global__ __launch_bounds__(512, 2) void lstm_seq(
    const uint32_t* __restrict__ xpk, const uint32_t* __restrict__ wrg,
    const uint4* __restrict__ wld, float* __restrict__ hfin) {
  __shared__ __align__(16) uint4 wsm[8 * 512];     // 64 KB weight tail
  __shared__ __align__(16) uint32_t hsm[128];      // 256 f16 h
  __shared__ __align__(16) float gsm[512];         // (f,o) activated pairs
  const int t0 = threadIdx.x, t1 = t0 + 512, b = blockIdx.x;
  const int lane = t0 & 63;

  uint32_t w0[112], w1[112];
#pragma unroll
  for (int c = 0; c < 112; ++c) { w0[c] = wrg[c * G4 + t0]; w1[c] = wrg[c * G4 + t1]; }
#pragma unroll
  for (int c = 0; c < 8; ++c) wsm[c * 512 + t0] = wld[c * 512 + t0];
  if (t0 < 128) hsm[t0] = 0;
  float cst = 0.f, hlast = 0.f;
  const uint32_t* xp = xpk + (size_t)b * TT * 512 + t0;
  uint32_t xn = xp[0];
  __syncthreads();

  for (int t = 0; t < TT; ++t) {
    const uint32_t xw = xn;
    xn = xp[(size_t)((t < TT - 1) ? t + 1 : t) * 512];   // prefetch next step
    // h distribute: lane l holds h dwords 2l (hv0), 2l+1 (hv1).
    uint2 hh2 = *(const uint2*)&hsm[2 * lane];
    uint32_t hv0 = hh2.x, hv1 = hh2.y;
    float a00 = 0.f, a01 = 0.f, a10 = 0.f, a11 = 0.f;
#pragma unroll
    for (int cc = 0; cc < 28; ++cc) {          // register-resident kpairs
      uint32_t hx = __builtin_amdgcn_readlane(hv0, 2 * cc);      // kpair 4cc+0
      uint32_t hy = __builtin_amdgcn_readlane(hv1, 2 * cc);      // kpair 4cc+1
      uint32_t hz = __builtin_amdgcn_readlane(hv0, 2 * cc + 1);  // kpair 4cc+2
      uint32_t hw = __builtin_amdgcn_readlane(hv1, 2 * cc + 1);  // kpair 4cc+3
      a00 = fdot2(w0[4 * cc + 0], hx, a00);
      a01 = fdot2(w0[4 * cc + 1], hy, a01);
      a00 = fdot2(w0[4 * cc + 2], hz, a00);
      a01 = fdot2(w0[4 * cc + 3], hw, a01);
      a10 = fdot2(w1[4 * cc + 0], hx, a10);
      a11 = fdot2(w1[4 * cc + 1], hy, a11);
      a10 = fdot2(w1[4 * cc + 2], hz, a10);
      a11 = fdot2(w1[4 * cc + 3], hw, a11);
    }
#pragma unroll
    for (int j = 0; j < 4; ++j) {              // LDS-resident tail kpairs
      uint32_t hx = __builtin_amdgcn_readlane(hv0, 56 + 2 * j);
      uint32_t hy = __builtin_amdgcn_readlane(hv1, 56 + 2 * j);
      uint32_t hz = __builtin_amdgcn_readlane(hv0, 57 + 2 * j);
      uint32_t hw = __builtin_amdgcn_readlane(hv1, 57 + 2 * j);
      uint4 wa = wsm[j * 512 + t0];
      uint4 wb = wsm[(4 + j) * 512 + t0];
      a00 = fdot2(wa.x, hx, a00);
      a01 = fdot2(wa.y, hy, a01);
      a00 = fdot2(wa.z, hz, a00);
      a01 = fdot2(wa.w, hw, a01);
      a10 = fdot2(wb.x, hx, a10);
      a11 = fdot2(wb.y, hy, a11);
      a10 = fdot2(wb.z, hz, a10);
      a11 = fdot2(wb.w, hw, a11);
    }
    half2v xh = __builtin_bit_cast(half2v, xw);
    const float s0 = (a00 + a01) + (float)xh.x;
    const float s1 = (a10 + a11) + (float)xh.y;
    float ig = 0.f, gg = 0.f;
    if (t0 < 256) {
      ig = sigmf(s0);                 // row t0       = i gate (pre-barrier)
      gg = tanhf2(s1);                // row t0+512   = g gate (pre-barrier)
    } else {
      float2 fo;                      // rows t0 (f), t0+512 (o): activate here
      fo.x = sigmf(s0);
      fo.y = sigmf(s1);
      *(float2*)&gsm[2 * (t0 - 256)] = fo;   // one ds_write_b64
    }
    bar_lds();
    if (t0 < 256) {
      float2 fo = *(const float2*)&gsm[2 * t0];  // one ds_read_b64
      cst = fo.x * cst + ig * gg;
      hlast = fo.y * tanhf2(cst);
      ((_Float16*)hsm)[t0] = (_Float16)hlast;
    }
    bar_lds();
  }
  if (t0 < 256) hfin[(size_t)b * HH + t0] = hlast;
}

// ---------------------------------------------------------------------------
// K3: out[b][c] = h_last[b] . W_cls[c] + b_cls[c]
// ---------------------------------------------------------------------------
__global__ __launch_bounds__(256) void cls_k(
    const float* __restrict__ hfin, const float* __restrict__ Wcls,
    const float* __restrict__ bcls, float* __restrict__ out) {
  __shared__ float part[4][NC];
  const int b = blockIdx.x, tid = threadIdx.x;
  const int lane = tid & 63, wave = tid >> 6;
  float hv = hfin[(size_t)b * HH + tid];
#pragma unroll
  for (int c = 0; c < NC; ++c) {
    float p = hv * Wcls[c * HH + tid];
#pragma unroll
    for (int off = 32; off >= 1; off >>= 1) p += __shfl_down(p, off, 64);
    if (lane == 0) part[wave][c] = p;
  }
  __syncthreads();
  if (tid < NC) {
    out[(size_t)b * NC + tid] =
        part[0][tid] + part[1][tid] + part[2][tid] + part[3][tid] + bcls[tid];
  }
}

// ---------------------------------------------------------------------------
extern "C" void kernel_launch(void* const* d_in, const int* in_sizes, int n_in,
                              void* d_out, int out_size, void* d_ws, size_t ws_size,
                              hipStream_t stream) {
  (void)in_sizes; (void)n_in; (void)out_size; (void)ws_size;
  const float* x    = (const float*)d_in[0];
  const float* key  = (const float*)d_in[1];
  const float* Wih  = (const float*)d_in[2];
  const float* Whh  = (const float*)d_in[3];
  const float* bih  = (const float*)d_in[4];
  const float* bhh  = (const float*)d_in[5];
  const float* Wcls = (const float*)d_in[6];
  const float* bcls = (const float*)d_in[7];
  float* out = (float*)d_out;

  char* ws = (char*)d_ws;
  size_t off = 0;
  uint32_t* xpk  = (uint32_t*)(ws + off); off += (size_t)BB * TT * 512 * 4;  // 268 MB
  uint32_t* wrg  = (uint32_t*)(ws + off); off += (size_t)112 * G4 * 4;
  uint32_t* wld  = (uint32_t*)(ws + off); off += (size_t)8 * 512 * 16;       // 64 KB
  _Float16* WcT  = (_Float16*)(ws + off); off += (size_t)G4 * II * 2;
  float* biasc   = (float*)(ws + off);    off += (size_t)G4 * 4;
  float* hfin    = (float*)(ws + off);    off += (size_t)BB * HH * 4;

  hipLaunchKernelGGL(prep_wc,  dim3(II),  dim3(G4),  0, stream, key, Wih, bih, bhh, WcT, biasc);
  hipLaunchKernelGGL(prep_whh, dim3(512), dim3(256), 0, stream, Whh, wrg, wld);
  hipLaunchKernelGGL(gemm_xproj, dim3(G4 / 128, (BB * TT) / 128), dim3(256), 0, stream,
                     x, WcT, biasc, (_Float16*)xpk);
  hipLaunchKernelGGL(lstm_seq, dim3(BB), dim3(512), 0, stream, xpk, wrg, (const uint4*)wld, hfin);
  hipLaunchKernelGGL(cls_k,    dim3(BB), dim3(256), 0, stream, hfin, Wcls, bcls, out);
}